// Round 11
// baseline (58.194 us; speedup 1.0000x reference)
//
#include <hip/hip_runtime.h>
#include <hip/hip_bf16.h>
#include <cmath>

// Problem constants: V=100000, E=128, B=32, S=1024, N=16
#define NS_ROWS    32768
#define NS_NEG     16
#define NS_TARGETS 17
#define NS_TILE    15            // rows per 1024-thread block (15*17*4 = 1020 lanes)
#define NS_CPAD    132           // padded ctx row stride (floats)
#define NS_V       100000
#define NS_E       128

typedef unsigned short u16;
typedef u16 u16x8 __attribute__((ext_vector_type(8)));

__device__ __forceinline__ float log_sigmoid_f(float x) {
    return fminf(x, 0.0f) - log1pf(__expf(-fabsf(x)));
}

__device__ __forceinline__ u16 f32_to_bf16_rne(float f) {
    union { float f; unsigned u; } v; v.f = f;
    const unsigned u = v.u + (0x7fffu + ((v.u >> 16) & 1u));
    return (u16)(u >> 16);
}
__device__ __forceinline__ float bf16_to_f32(u16 h) {
    union { unsigned u; float f; } v; v.u = ((unsigned)h) << 16;
    return v.f;
}

// Pass 1: W f32 [V,128] -> bf16 table in d_ws (halves the random-gather bytes).
__global__ __launch_bounds__(256) void ns_convert_kernel(
    const float* __restrict__ W, u16* __restrict__ Wbf)
{
    const size_t base = ((size_t)blockIdx.x * 256 + threadIdx.x) * 8;
    if (base >= (size_t)NS_V * NS_E) return;
    const float4 a = *reinterpret_cast<const float4*>(W + base);
    const float4 b = *reinterpret_cast<const float4*>(W + base + 4);
    u16x8 o;
    o[0]=f32_to_bf16_rne(a.x); o[1]=f32_to_bf16_rne(a.y);
    o[2]=f32_to_bf16_rne(a.z); o[3]=f32_to_bf16_rne(a.w);
    o[4]=f32_to_bf16_rne(b.x); o[5]=f32_to_bf16_rne(b.y);
    o[6]=f32_to_bf16_rne(b.z); o[7]=f32_to_bf16_rne(b.w);
    *reinterpret_cast<u16x8*>(Wbf + base) = o;
}

// Pass 2: R3 carrier (quads over 15-row tile, ctx staged f32 in LDS),
// W gathers in bf16: 4 x 16B chunks per quad-lane (one 64B line per quad-step).
__global__ __launch_bounds__(1024) void ns_main_bf16_kernel(
    const int*   __restrict__ sentence,
    const float* __restrict__ context,
    const int*   __restrict__ neg,
    const u16*   __restrict__ Wbf,
    float*       __restrict__ out)
{
    __shared__ float cctx[NS_TILE][NS_CPAD];
    __shared__ float wsum[16];

    const int tid     = threadIdx.x;
    const int rowbase = blockIdx.x * NS_TILE;

    const int group = tid >> 2;               // 0..255
    const int sub   = tid & 3;
    const int lrow  = group / NS_TARGETS;     // 0..15
    const int tgt   = group - lrow * NS_TARGETS;
    const int row   = rowbase + lrow;
    const bool active = (lrow < NS_TILE) && (row < NS_ROWS);

    // issue bf16 gathers early: lane sub reads ushort8 chunks {sub+4k}
    u16x8 g0, g1, g2, g3;
    if (active) {
        const int idx = (tgt == 0) ? sentence[row] : neg[(row << 4) + (tgt - 1)];
        const u16x8* __restrict__ wr =
            reinterpret_cast<const u16x8*>(Wbf + (size_t)idx * NS_E) + sub;
        g0 = wr[0]; g1 = wr[4]; g2 = wr[8]; g3 = wr[12];
    } else {
        g0 = g1 = g2 = g3 = (u16x8)0;
    }

    // stage 15 ctx rows (f32) into LDS, coalesced float4
    if (tid < NS_TILE * 32) {
        const int r = tid >> 5, e4 = tid & 31;
        const int grow = rowbase + r;
        if (grow < NS_ROWS) {
            const float4 v = reinterpret_cast<const float4*>(context)[grow * 32 + e4];
            *reinterpret_cast<float4*>(&cctx[r][e4 * 4]) = v;
        }
    }
    __syncthreads();

    float loss = 0.0f;
    if (active) {
        const float4* cr = reinterpret_cast<const float4*>(&cctx[lrow][0]);
        float acc = 0.0f;
        // chunk sub+4k covers elems [8*(sub+4k), +8) -> ctx float4 {2sub+8k, +1}
#define NS_CHUNK(g, k)                                                        \
        {                                                                     \
            const float4 ca = cr[2 * sub + 8 * (k)];                          \
            const float4 cb = cr[2 * sub + 8 * (k) + 1];                      \
            acc += bf16_to_f32(g[0]) * ca.x + bf16_to_f32(g[1]) * ca.y        \
                 + bf16_to_f32(g[2]) * ca.z + bf16_to_f32(g[3]) * ca.w        \
                 + bf16_to_f32(g[4]) * cb.x + bf16_to_f32(g[5]) * cb.y        \
                 + bf16_to_f32(g[6]) * cb.z + bf16_to_f32(g[7]) * cb.w;       \
        }
        NS_CHUNK(g0, 0) NS_CHUNK(g1, 1) NS_CHUNK(g2, 2) NS_CHUNK(g3, 3)
#undef NS_CHUNK
        acc += __shfl_xor(acc, 1, 64);
        acc += __shfl_xor(acc, 2, 64);
        if (sub == 0) loss = log_sigmoid_f((tgt == 0) ? acc : -acc);
    }

#pragma unroll
    for (int m = 32; m >= 1; m >>= 1) loss += __shfl_xor(loss, m, 64);

    const int wave = tid >> 6, lane = tid & 63;
    if (lane == 0) wsum[wave] = loss;
    __syncthreads();
    if (tid == 0) {
        float t = 0.0f;
#pragma unroll
        for (int i = 0; i < 16; ++i) t += wsum[i];
        atomicAdd(out, -t);
    }
}

// Fallback (ws too small): R3's f32 kernel, verbatim structure.
__global__ __launch_bounds__(1024) void ns_main_f32_kernel(
    const int*   __restrict__ sentence,
    const float* __restrict__ context,
    const int*   __restrict__ neg,
    const float* __restrict__ W,
    float*       __restrict__ out)
{
    __shared__ float cctx[NS_TILE][NS_CPAD];
    __shared__ float wsum[16];

    const int tid     = threadIdx.x;
    const int rowbase = blockIdx.x * NS_TILE;
    const int group = tid >> 2;
    const int sub   = tid & 3;
    const int lrow  = group / NS_TARGETS;
    const int tgt   = group - lrow * NS_TARGETS;
    const int row   = rowbase + lrow;
    const bool active = (lrow < NS_TILE) && (row < NS_ROWS);

    float4 w0, w1, w2, w3, w4, w5, w6, w7;
    if (active) {
        const int idx = (tgt == 0) ? sentence[row] : neg[(row << 4) + (tgt - 1)];
        const float4* __restrict__ wr =
            reinterpret_cast<const float4*>(W) + (size_t)idx * 32 + sub;
        w0 = wr[0];  w1 = wr[4];  w2 = wr[8];  w3 = wr[12];
        w4 = wr[16]; w5 = wr[20]; w6 = wr[24]; w7 = wr[28];
    } else {
        w0=w1=w2=w3=w4=w5=w6=w7 = make_float4(0.f,0.f,0.f,0.f);
    }

    if (tid < NS_TILE * 32) {
        const int r = tid >> 5, e4 = tid & 31;
        const int grow = rowbase + r;
        if (grow < NS_ROWS) {
            const float4 v = reinterpret_cast<const float4*>(context)[grow * 32 + e4];
            *reinterpret_cast<float4*>(&cctx[r][e4 * 4]) = v;
        }
    }
    __syncthreads();

    float loss = 0.0f;
    if (active) {
        const float4* cr = reinterpret_cast<const float4*>(&cctx[lrow][0]);
        float acc;
        acc  = w0.x*cr[sub+ 0].x + w0.y*cr[sub+ 0].y + w0.z*cr[sub+ 0].z + w0.w*cr[sub+ 0].w;
        acc += w1.x*cr[sub+ 4].x + w1.y*cr[sub+ 4].y + w1.z*cr[sub+ 4].z + w1.w*cr[sub+ 4].w;
        acc += w2.x*cr[sub+ 8].x + w2.y*cr[sub+ 8].y + w2.z*cr[sub+ 8].z + w2.w*cr[sub+ 8].w;
        acc += w3.x*cr[sub+12].x + w3.y*cr[sub+12].y + w3.z*cr[sub+12].z + w3.w*cr[sub+12].w;
        acc += w4.x*cr[sub+16].x + w4.y*cr[sub+16].y + w4.z*cr[sub+16].z + w4.w*cr[sub+16].w;
        acc += w5.x*cr[sub+20].x + w5.y*cr[sub+20].y + w5.z*cr[sub+20].z + w5.w*cr[sub+20].w;
        acc += w6.x*cr[sub+24].x + w6.y*cr[sub+24].y + w6.z*cr[sub+24].z + w6.w*cr[sub+24].w;
        acc += w7.x*cr[sub+28].x + w7.y*cr[sub+28].y + w7.z*cr[sub+28].z + w7.w*cr[sub+28].w;
        acc += __shfl_xor(acc, 1, 64);
        acc += __shfl_xor(acc, 2, 64);
        if (sub == 0) loss = log_sigmoid_f((tgt == 0) ? acc : -acc);
    }

#pragma unroll
    for (int m = 32; m >= 1; m >>= 1) loss += __shfl_xor(loss, m, 64);

    const int wave = tid >> 6, lane = tid & 63;
    if (lane == 0) wsum[wave] = loss;
    __syncthreads();
    if (tid == 0) {
        float t = 0.0f;
#pragma unroll
        for (int i = 0; i < 16; ++i) t += wsum[i];
        atomicAdd(out, -t);
    }
}

extern "C" void kernel_launch(void* const* d_in, const int* in_sizes, int n_in,
                              void* d_out, int out_size, void* d_ws, size_t ws_size,
                              hipStream_t stream) {
    const int*   sentence = (const int*)d_in[0];
    const float* context  = (const float*)d_in[1];
    const int*   neg      = (const int*)d_in[2];
    const float* W        = (const float*)d_in[3];
    float*       out      = (float*)d_out;

    hipMemsetAsync(out, 0, sizeof(float), stream);

    const int blocks = (NS_ROWS + NS_TILE - 1) / NS_TILE;  // 2185
    const size_t need = (size_t)NS_V * NS_E * sizeof(u16); // 25.6 MB

    if (ws_size >= need) {
        u16* Wbf = (u16*)d_ws;
        const int cblocks = (NS_V * NS_E / 8 + 255) / 256; // 6250
        ns_convert_kernel<<<cblocks, 256, 0, stream>>>(W, Wbf);
        ns_main_bf16_kernel<<<blocks, 1024, 0, stream>>>(sentence, context, neg, Wbf, out);
    } else {
        ns_main_f32_kernel<<<blocks, 1024, 0, stream>>>(sentence, context, neg, W, out);
    }
}